// Round 5
// baseline (31.619 us; speedup 1.0000x reference)
//
#include <hip/hip_runtime.h>
#include <math.h>

#define NANCH 8400
#define ROWL  37
#define H0    2160
#define W0    3840
#define HW    (H0 * W0)
#define NPART 33

typedef unsigned long long u64;
typedef float f4 __attribute__((ext_vector_type(4)));

// ws layout: u64 keyT[33] | u64 keyF[33] | float bmax[33]
// key = (float_bits(score) << 32) | (NANCH - idx); scores >= 0 so raw bits
// are monotonic; larger (NANCH-idx) = smaller idx wins ties (top_k order).

// ---------------------------------------------------------------------------
// K1: score reduction. 33 blocks x 256 threads, one anchor per thread.
// Emits per-block sortable keys (SoA) for a branch-free merge in K2.
// ---------------------------------------------------------------------------
__global__ __launch_bounds__(256) void k_score(const float* __restrict__ pred,
                                               float* __restrict__ wsf) {
    int tid = threadIdx.x;
    int a = blockIdx.x * 256 + tid;

    float bmax = -1e30f;
    float vT = -1e30f, vF = -1e30f;
    int   iT = 0, iF = 0;

    if (a < NANCH) {
        const float* row = pred + a * ROWL;
        float cx = row[0], cy = row[1], w = row[2], h = row[3];
        bmax = fmaxf(fmaxf(cx, cy), fmaxf(w, h));

        float l  = row[4];
        float sc = 1.0f / (1.0f + expf(-l));
        float base = fmaxf(sc - 0.5f, 0.0f) + 0.001f;

        float sum = 0.0f;
#pragma unroll
        for (int j = 0; j < 32; ++j) sum += fabsf(row[5 + j]);
        float sb = base * (sum * 0.03125f);   // global maskness norm is argmax-invariant

        float cx6 = cx * 640.0f, cy6 = cy * 640.0f;
        float dxT = fabsf(cx6 - 320.0f) / 320.0f;
        float dyT = fabsf(cy6 - 320.0f) / 320.0f;
        float cwT = fminf(fmaxf(1.0f - 0.5f * (dxT + dyT), 0.0f), 1.0f);
        float dxF = fabsf(cx - 320.0f) / 320.0f;
        float dyF = fabsf(cy - 320.0f) / 320.0f;
        float cwF = fminf(fmaxf(1.0f - 0.5f * (dxF + dyF), 0.0f), 1.0f);

        vT = sb * (0.5f + 0.5f * cwT); iT = a;
        vF = sb * (0.5f + 0.5f * cwF); iF = a;
    }

    __shared__ float sb_[256];
    __shared__ float svT[256]; __shared__ int siT[256];
    __shared__ float svF[256]; __shared__ int siF[256];
    sb_[tid] = bmax;
    svT[tid] = vT; siT[tid] = iT;
    svF[tid] = vF; siF[tid] = iF;
    __syncthreads();

    for (int off = 128; off > 0; off >>= 1) {
        if (tid < off) {
            sb_[tid] = fmaxf(sb_[tid], sb_[tid + off]);
            float ov = svT[tid + off]; int oi = siT[tid + off];
            if (ov > svT[tid] || (ov == svT[tid] && oi < siT[tid])) { svT[tid] = ov; siT[tid] = oi; }
            ov = svF[tid + off]; oi = siF[tid + off];
            if (ov > svF[tid] || (ov == svF[tid] && oi < siF[tid])) { svF[tid] = ov; siF[tid] = oi; }
        }
        __syncthreads();
    }

    if (tid == 0) {
        u64* kT = (u64*)wsf;
        u64* kF = kT + NPART;
        float* bm = (float*)(kT + 2 * NPART);
        kT[blockIdx.x] = ((u64)__float_as_uint(svT[0]) << 32) | (u64)(unsigned)(NANCH - siT[0]);
        kF[blockIdx.x] = ((u64)__float_as_uint(svF[0]) << 32) | (u64)(unsigned)(NANCH - siF[0]);
        bm[blockIdx.x] = sb_[0];
    }
}

// ---------------------------------------------------------------------------
// sigmoid(bilinear160(coef . proto)) at one 640-grid point. Same op order as
// round-1 (bitwise match).
// ---------------------------------------------------------------------------
__device__ __forceinline__ float sig_eval(int gy, int gx,
                                          const float* __restrict__ proto,
                                          const float* c) {
    float yf = gy * 0.25f - 0.375f;
    int q = (int)floorf(yf); float wy = yf - (float)q;
    float xf = gx * 0.25f - 0.375f;
    int r = (int)floorf(xf); float wx = xf - (float)r;
    int qy0 = max(q, 0), qy1 = min(q + 1, 159);
    int qx0 = max(r, 0), qx1 = min(r + 1, 159);
    int p00 = qy0 * 160 + qx0, p01 = qy0 * 160 + qx1;
    int p10 = qy1 * 160 + qx0, p11 = qy1 * 160 + qx1;
    float a = 0.f, b = 0.f, cc = 0.f, d = 0.f;
#pragma unroll
    for (int j = 0; j < 32; ++j) {
        const float* pj = proto + j * 25600;
        float cf = c[j];
        a  += cf * pj[p00]; b += cf * pj[p01];
        cc += cf * pj[p10]; d += cf * pj[p11];
    }
    float L = (1.0f - wy) * ((1.0f - wx) * a + wx * b)
            +         wy  * ((1.0f - wx) * cc + wx * d);
    return 1.0f / (1.0f + expf(-L));
}

// ---------------------------------------------------------------------------
// K2: single output sweep. Zero-stores issue FIRST (no dependencies), then
// the branch-free scalar merge runs hidden under the store drain (a wave
// cannot end until its stores retire). Rare in-rect threads wait vmcnt(0)
// and overwrite their quad with masked pixels.
// ---------------------------------------------------------------------------
__global__ __launch_bounds__(256) void k_paint(const float* __restrict__ x_raw,
                                               const float* __restrict__ pred,
                                               const float* __restrict__ proto,
                                               const float* __restrict__ wsf,
                                               float* __restrict__ out) {
    int t   = blockIdx.x * 256 + threadIdx.x;
    int pix = t * 4;            // == Y*3840 + X0

    // ---- unconditional zero stores: the bulk traffic, zero-dependency ----
    f4 z = {0.f, 0.f, 0.f, 0.f};
    *(f4*)(out + pix)          = z;
    *(f4*)(out + HW + pix)     = z;
    *(f4*)(out + 2 * HW + pix) = z;

    // ---- branch-free scalar merge (hidden under store drain) ----
    const u64*  kT = (const u64*)wsf;
    const u64*  kF = kT + NPART;
    const float* bm = (const float*)(kT + 2 * NPART);
    u64 mT = 0, mF = 0; float bx = -1e30f;
#pragma unroll
    for (int b = 0; b < NPART; ++b) {
        u64 a = kT[b]; if (a > mT) mT = a;
        u64 c = kF[b]; if (c > mF) mF = c;
        bx = fmaxf(bx, bm[b]);
    }
    u64 sel = (bx <= 1.2f) ? mT : mF;
    int bi = NANCH - (int)(unsigned)(sel & 0xFFFFFFFFu);

    const float* row = pred + bi * ROWL;
    float cx = row[0], cy = row[1], w = row[2], h = row[3];
    float x1 = fminf(fmaxf(cx - w * 0.5f, 0.0f), 639.0f);
    float y1 = fminf(fmaxf(cy - h * 0.5f, 0.0f), 639.0f);
    float x2 = fminf(fmaxf(cx + w * 0.5f, 0.0f), 639.0f);
    float y2 = fminf(fmaxf(cy + h * 0.5f, 0.0f), 639.0f);
    float fbx = x1 * 6.0f;      // sx = 3840/640
    float fby = y1 * 3.375f;    // sy = 2160/640
    float fbz = x2 * 6.0f;
    float fbw = y2 * 3.375f;

    int Y  = t / 960;
    int X0 = (t - Y * 960) * 4;
    float ysf = (float)Y;
    bool inrect = (ysf >= fby) && (ysf < fbw)
               && ((float)(X0 + 3) >= fbx) && ((float)X0 < fbz);
    if (!inrect) return;

    // ---- rare path: evaluate mask on the fly ----
    float c[32];
#pragma unroll
    for (int j = 0; j < 32; ++j) c[j] = row[5 + j];

    float yf = (ysf + 0.5f) / 3.375f - 0.5f;
    int   y0 = (int)floorf(yf);
    float wy = yf - (float)y0;
    int y0c = max(y0, 0), y1c = min(y0 + 1, 639);

    float m[4];
    bool any = false;
#pragma unroll
    for (int k = 0; k < 4; ++k) {
        float xs = (float)(X0 + k);
        bool rect = (xs >= fbx) && (xs < fbz);
        m[k] = 0.0f;
        if (rect) {
            float xf = (xs + 0.5f) / 6.0f - 0.5f;
            int   x0 = (int)floorf(xf);
            float wx = xf - (float)x0;
            int x0c = max(x0, 0), x1c = min(x0 + 1, 639);
            float s00 = sig_eval(y0c, x0c, proto, c);
            float s01 = sig_eval(y0c, x1c, proto, c);
            float s10 = sig_eval(y1c, x0c, proto, c);
            float s11 = sig_eval(y1c, x1c, proto, c);
            float v = (1.0f - wy) * ((1.0f - wx) * s00 + wx * s01)
                    +         wy  * ((1.0f - wx) * s10 + wx * s11);
            if (v > 0.72f) { m[k] = 1.0f; any = true; }
        }
    }
    if (!any) return;

    // ensure our zeros retired before overwriting the same addresses
    asm volatile("s_waitcnt vmcnt(0)" ::: "memory");

    float4 xa = *(const float4*)(x_raw + pix);
    float4 xb = *(const float4*)(x_raw + HW + pix);
    float4 xc = *(const float4*)(x_raw + 2 * HW + pix);
#define CLIP255(v) fminf(fmaxf((v) * 255.0f, 0.0f), 255.0f)
    f4 o0 = {m[0] * CLIP255(xa.x), m[1] * CLIP255(xa.y),
             m[2] * CLIP255(xa.z), m[3] * CLIP255(xa.w)};
    f4 o1 = {m[0] * CLIP255(xb.x), m[1] * CLIP255(xb.y),
             m[2] * CLIP255(xb.z), m[3] * CLIP255(xb.w)};
    f4 o2 = {m[0] * CLIP255(xc.x), m[1] * CLIP255(xc.y),
             m[2] * CLIP255(xc.z), m[3] * CLIP255(xc.w)};
#undef CLIP255
    *(f4*)(out + pix)          = o0;
    *(f4*)(out + HW + pix)     = o1;
    *(f4*)(out + 2 * HW + pix) = o2;
}

// ---------------------------------------------------------------------------
extern "C" void kernel_launch(void* const* d_in, const int* in_sizes, int n_in,
                              void* d_out, int out_size, void* d_ws, size_t ws_size,
                              hipStream_t stream) {
    const float* x_raw = (const float*)d_in[0];
    const float* pred  = (const float*)d_in[1];
    const float* proto = (const float*)d_in[2];
    float* out = (float*)d_out;
    float* wsf = (float*)d_ws;

    k_score<<<dim3(NPART), dim3(256), 0, stream>>>(pred, wsf);
    k_paint<<<dim3(8100),  dim3(256), 0, stream>>>(x_raw, pred, proto, wsf, out);
}

// Round 6
// 30.633 us; speedup vs baseline: 1.0322x; 1.0322x over previous
//
#include <hip/hip_runtime.h>
#include <math.h>

#define NANCH 8400
#define ROWL  37
#define H0    2160
#define W0    3840
#define HW    (H0 * W0)
#define NPART 33

typedef unsigned long long u64;
typedef float f4 __attribute__((ext_vector_type(4)));

// ws layout: u64 keyT[33] | u64 keyF[33] | float bmax[33]
// key = (float_bits(score) << 32) | (NANCH - idx); scores >= 0 so raw bits
// are monotonic; larger (NANCH-idx) = smaller idx wins ties (top_k order).

// ---------------------------------------------------------------------------
// K1: score reduction. 33 blocks x 256 threads, one anchor per thread.
// Emits per-block sortable keys (SoA) for a branch-free scalar merge in K2.
// ---------------------------------------------------------------------------
__global__ __launch_bounds__(256) void k_score(const float* __restrict__ pred,
                                               float* __restrict__ wsf) {
    int tid = threadIdx.x;
    int a = blockIdx.x * 256 + tid;

    float bmax = -1e30f;
    float vT = -1e30f, vF = -1e30f;
    int   iT = 0, iF = 0;

    if (a < NANCH) {
        const float* row = pred + a * ROWL;
        float cx = row[0], cy = row[1], w = row[2], h = row[3];
        bmax = fmaxf(fmaxf(cx, cy), fmaxf(w, h));

        float l  = row[4];
        float sc = 1.0f / (1.0f + expf(-l));
        float base = fmaxf(sc - 0.5f, 0.0f) + 0.001f;

        float sum = 0.0f;
#pragma unroll
        for (int j = 0; j < 32; ++j) sum += fabsf(row[5 + j]);
        float sb = base * (sum * 0.03125f);   // global maskness norm is argmax-invariant

        float cx6 = cx * 640.0f, cy6 = cy * 640.0f;
        float dxT = fabsf(cx6 - 320.0f) / 320.0f;
        float dyT = fabsf(cy6 - 320.0f) / 320.0f;
        float cwT = fminf(fmaxf(1.0f - 0.5f * (dxT + dyT), 0.0f), 1.0f);
        float dxF = fabsf(cx - 320.0f) / 320.0f;
        float dyF = fabsf(cy - 320.0f) / 320.0f;
        float cwF = fminf(fmaxf(1.0f - 0.5f * (dxF + dyF), 0.0f), 1.0f);

        vT = sb * (0.5f + 0.5f * cwT); iT = a;
        vF = sb * (0.5f + 0.5f * cwF); iF = a;
    }

    __shared__ float sb_[256];
    __shared__ float svT[256]; __shared__ int siT[256];
    __shared__ float svF[256]; __shared__ int siF[256];
    sb_[tid] = bmax;
    svT[tid] = vT; siT[tid] = iT;
    svF[tid] = vF; siF[tid] = iF;
    __syncthreads();

    for (int off = 128; off > 0; off >>= 1) {
        if (tid < off) {
            sb_[tid] = fmaxf(sb_[tid], sb_[tid + off]);
            float ov = svT[tid + off]; int oi = siT[tid + off];
            if (ov > svT[tid] || (ov == svT[tid] && oi < siT[tid])) { svT[tid] = ov; siT[tid] = oi; }
            ov = svF[tid + off]; oi = siF[tid + off];
            if (ov > svF[tid] || (ov == svF[tid] && oi < siF[tid])) { svF[tid] = ov; siF[tid] = oi; }
        }
        __syncthreads();
    }

    if (tid == 0) {
        u64* kT = (u64*)wsf;
        u64* kF = kT + NPART;
        float* bm = (float*)(kT + 2 * NPART);
        kT[blockIdx.x] = ((u64)__float_as_uint(svT[0]) << 32) | (u64)(unsigned)(NANCH - siT[0]);
        kF[blockIdx.x] = ((u64)__float_as_uint(svF[0]) << 32) | (u64)(unsigned)(NANCH - siF[0]);
        bm[blockIdx.x] = sb_[0];
    }
}

// ---------------------------------------------------------------------------
// sigmoid(bilinear160(coef . proto)) at one 640-grid point. Same op order as
// round-1 (bitwise match).
// ---------------------------------------------------------------------------
__device__ __forceinline__ float sig_eval(int gy, int gx,
                                          const float* __restrict__ proto,
                                          const float* c) {
    float yf = gy * 0.25f - 0.375f;
    int q = (int)floorf(yf); float wy = yf - (float)q;
    float xf = gx * 0.25f - 0.375f;
    int r = (int)floorf(xf); float wx = xf - (float)r;
    int qy0 = max(q, 0), qy1 = min(q + 1, 159);
    int qx0 = max(r, 0), qx1 = min(r + 1, 159);
    int p00 = qy0 * 160 + qx0, p01 = qy0 * 160 + qx1;
    int p10 = qy1 * 160 + qx0, p11 = qy1 * 160 + qx1;
    float a = 0.f, b = 0.f, cc = 0.f, d = 0.f;
#pragma unroll
    for (int j = 0; j < 32; ++j) {
        const float* pj = proto + j * 25600;
        float cf = c[j];
        a  += cf * pj[p00]; b += cf * pj[p01];
        cc += cf * pj[p10]; d += cf * pj[p11];
    }
    float L = (1.0f - wy) * ((1.0f - wx) * a + wx * b)
            +         wy  * ((1.0f - wx) * cc + wx * d);
    return 1.0f / (1.0f + expf(-L));
}

// ---------------------------------------------------------------------------
// K2: single output sweep, R4 ordering (merge FIRST — no vector stores in
// flight, so the uniform key loads take the SMEM scalar path), then one
// non-temporal store per address (zeros or painted pixels).
// ---------------------------------------------------------------------------
__global__ __launch_bounds__(256) void k_paint(const float* __restrict__ x_raw,
                                               const float* __restrict__ pred,
                                               const float* __restrict__ proto,
                                               const float* __restrict__ wsf,
                                               float* __restrict__ out) {
    int t   = blockIdx.x * 256 + threadIdx.x;
    int pix = t * 4;            // == Y*3840 + X0

    // ---- branch-free scalar merge (SMEM path; no stores issued yet) ----
    const u64*   kT = (const u64*)wsf;
    const u64*   kF = kT + NPART;
    const float* bm = (const float*)(kT + 2 * NPART);
    u64 mT = 0, mF = 0; float bx = -1e30f;
#pragma unroll
    for (int b = 0; b < NPART; ++b) {
        u64 a = kT[b]; if (a > mT) mT = a;
        u64 c = kF[b]; if (c > mF) mF = c;
        bx = fmaxf(bx, bm[b]);
    }
    u64 sel = (bx <= 1.2f) ? mT : mF;
    int bi = NANCH - (int)(unsigned)(sel & 0xFFFFFFFFu);

    const float* row = pred + bi * ROWL;
    float cx = row[0], cy = row[1], w = row[2], h = row[3];
    float x1 = fminf(fmaxf(cx - w * 0.5f, 0.0f), 639.0f);
    float y1 = fminf(fmaxf(cy - h * 0.5f, 0.0f), 639.0f);
    float x2 = fminf(fmaxf(cx + w * 0.5f, 0.0f), 639.0f);
    float y2 = fminf(fmaxf(cy + h * 0.5f, 0.0f), 639.0f);
    float fbx = x1 * 6.0f;      // sx = 3840/640
    float fby = y1 * 3.375f;    // sy = 2160/640
    float fbz = x2 * 6.0f;
    float fbw = y2 * 3.375f;

    int Y  = t / 960;
    int X0 = (t - Y * 960) * 4;
    float ysf = (float)Y;
    bool inrect = (ysf >= fby) && (ysf < fbw)
               && ((float)(X0 + 3) >= fbx) && ((float)X0 < fbz);

    f4 o0 = {0.f, 0.f, 0.f, 0.f};
    f4 o1 = o0, o2 = o0;

    if (inrect) {
        float c[32];
#pragma unroll
        for (int j = 0; j < 32; ++j) c[j] = row[5 + j];

        float yf = (ysf + 0.5f) / 3.375f - 0.5f;
        int   y0 = (int)floorf(yf);
        float wy = yf - (float)y0;
        int y0c = max(y0, 0), y1c = min(y0 + 1, 639);

        float m[4];
        bool any = false;
#pragma unroll
        for (int k = 0; k < 4; ++k) {
            float xs = (float)(X0 + k);
            bool rect = (xs >= fbx) && (xs < fbz);
            m[k] = 0.0f;
            if (rect) {
                float xf = (xs + 0.5f) / 6.0f - 0.5f;
                int   x0 = (int)floorf(xf);
                float wx = xf - (float)x0;
                int x0c = max(x0, 0), x1c = min(x0 + 1, 639);
                float s00 = sig_eval(y0c, x0c, proto, c);
                float s01 = sig_eval(y0c, x1c, proto, c);
                float s10 = sig_eval(y1c, x0c, proto, c);
                float s11 = sig_eval(y1c, x1c, proto, c);
                float v = (1.0f - wy) * ((1.0f - wx) * s00 + wx * s01)
                        +         wy  * ((1.0f - wx) * s10 + wx * s11);
                if (v > 0.72f) { m[k] = 1.0f; any = true; }
            }
        }
        if (any) {
            float4 xa = *(const float4*)(x_raw + pix);
            float4 xb = *(const float4*)(x_raw + HW + pix);
            float4 xc = *(const float4*)(x_raw + 2 * HW + pix);
#define CLIP255(v) fminf(fmaxf((v) * 255.0f, 0.0f), 255.0f)
            o0 = (f4){m[0] * CLIP255(xa.x), m[1] * CLIP255(xa.y),
                      m[2] * CLIP255(xa.z), m[3] * CLIP255(xa.w)};
            o1 = (f4){m[0] * CLIP255(xb.x), m[1] * CLIP255(xb.y),
                      m[2] * CLIP255(xb.z), m[3] * CLIP255(xb.w)};
            o2 = (f4){m[0] * CLIP255(xc.x), m[1] * CLIP255(xc.y),
                      m[2] * CLIP255(xc.z), m[3] * CLIP255(xc.w)};
#undef CLIP255
        }
    }

    // single non-temporal store per address (write-once stream, never re-read)
    __builtin_nontemporal_store(o0, (f4*)(out + pix));
    __builtin_nontemporal_store(o1, (f4*)(out + HW + pix));
    __builtin_nontemporal_store(o2, (f4*)(out + 2 * HW + pix));
}

// ---------------------------------------------------------------------------
extern "C" void kernel_launch(void* const* d_in, const int* in_sizes, int n_in,
                              void* d_out, int out_size, void* d_ws, size_t ws_size,
                              hipStream_t stream) {
    const float* x_raw = (const float*)d_in[0];
    const float* pred  = (const float*)d_in[1];
    const float* proto = (const float*)d_in[2];
    float* out = (float*)d_out;
    float* wsf = (float*)d_ws;

    k_score<<<dim3(NPART), dim3(256), 0, stream>>>(pred, wsf);
    k_paint<<<dim3(8100),  dim3(256), 0, stream>>>(x_raw, pred, proto, wsf, out);
}